// Round 14
// baseline (788.087 us; speedup 1.0000x reference)
//
#include <hip/hip_runtime.h>
#include <stdint.h>

typedef unsigned short u16;
typedef __attribute__((ext_vector_type(8))) _Float16 half8;
typedef __attribute__((ext_vector_type(4))) _Float16 half4;
typedef __attribute__((ext_vector_type(4))) float floatx4;

// ---------- helpers ----------
__device__ inline float bflo(unsigned u){ return __uint_as_float(u << 16); }
__device__ inline float bfhi(unsigned u){ return __uint_as_float(u & 0xffff0000u); }
__device__ inline float bf1(u16 v){ return __uint_as_float(((unsigned)v) << 16); }
__device__ inline u16 f2bf(float f){
  unsigned u = __float_as_uint(f);
  u += 0x7fffu + ((u >> 16) & 1u);           // RNE
  return (u16)(u >> 16);
}
__device__ inline float dot8(uint4 w, float4 a, float4 b, float acc){
  acc = fmaf(bflo(w.x), a.x, acc); acc = fmaf(bfhi(w.x), a.y, acc);
  acc = fmaf(bflo(w.y), a.z, acc); acc = fmaf(bfhi(w.y), a.w, acc);
  acc = fmaf(bflo(w.z), b.x, acc); acc = fmaf(bfhi(w.z), b.y, acc);
  acc = fmaf(bflo(w.w), b.z, acc); acc = fmaf(bfhi(w.w), b.w, acc);
  return acc;
}

// canonical weight buffer offsets (u16 elements), d_in order (skipping inputs)
#define CW_SLOTS 0
#define CW_GIN   4096
#define CW_BIN   4352
#define CW_GS    4608
#define CW_BS    4864
#define CW_GM    5120
#define CW_BM    5376
#define CW_WQ    5632
#define CW_WK    71168
#define CW_WV    136704
#define CW_WIH   202240
#define CW_WHH   398848
#define CW_BIH   595456
#define CW_BHH   596224
#define CW_W1    596992
#define CW_B1    728064
#define CW_W2    728576
#define CW_B2    859648
#define CW_TOTAL 859904

// ---------- dtype probe ----------
__global__ void k_flag(const u16* __restrict__ probe, int* __restrict__ flag){
  int t = threadIdx.x;
  int bad = 0;
  #pragma unroll
  for (int i = 0; i < 4; i++){
    float x = bf1(probe[t + i * 256]);
    if (!(fabsf(x) < 1e6f)) bad = 1;
  }
  __shared__ int s;
  if (t == 0) s = 0;
  __syncthreads();
  if (bad) atomicOr(&s, 1);
  __syncthreads();
  if (t == 0) *flag = s;
}

// ---------- canonicalize all weight/bias arrays to bf16 in ws ----------
struct CanonArgs { const void* p[18]; };

__global__ void k_canon(CanonArgs a, const int* __restrict__ flag, u16* __restrict__ cw){
  const int off[19] = {CW_SLOTS, CW_GIN, CW_BIN, CW_GS, CW_BS, CW_GM, CW_BM, CW_WQ,
                       CW_WK, CW_WV, CW_WIH, CW_WHH, CW_BIH, CW_BHH, CW_W1, CW_B1,
                       CW_W2, CW_B2, CW_TOTAL};
  int i = blockIdx.x * 256 + threadIdx.x;
  if (i >= CW_TOTAL) return;
  int f32m = *flag;
  int j = 0;
  while (i >= off[j + 1]) j++;
  int local = i - off[j];
  float v = f32m ? ((const float*)a.p[j])[local] : bf1(((const u16*)a.p[j])[local]);
  cw[i] = f2bf(v);
}

// ---------- init: wkvh[c][d] = Wkv[c][d]*gin[d] (fp16); broadcast slots -> f32 ----------
__global__ void k_init(const u16* __restrict__ cw, float* __restrict__ slots,
                       _Float16* __restrict__ wkvh)
{
  int idx = blockIdx.x * 256 + threadIdx.x;      // 0..262143
  if (idx < 131072){
    float g = bf1(cw[CW_GIN + (idx & 255)]);
    wkvh[idx] = (_Float16)(bf1(cw[CW_WK + idx]) * g);   // Wk|Wv contiguous
  } else {
    int i = idx - 131072;
    int d = i & 255;
    int q = (i >> 8) & 15;
    slots[i] = bf1(cw[CW_SLOTS + q * 256 + d]);
  }
}

// beta[c] = sum_d bin[d] * Wkv[c][d]  (512 cols)
__global__ void k_beta(const u16* __restrict__ cw, float* __restrict__ beta){
  int c = blockIdx.x * 256 + threadIdx.x;
  if (c >= 512) return;
  float a = 0.f;
  for (int d = 0; d < 256; d++)
    a = fmaf(bf1(cw[CW_BIN + d]), bf1(cw[CW_WK + c * 256 + d]), a);
  beta[c] = a;
}

// ---------- K0: per-row LN stats (mu, rstd); 16 lanes per row ----------
__global__ __launch_bounds__(256) void k0_stats(
    const void* __restrict__ inp, const int* __restrict__ flag, float2* __restrict__ stats)
{
  int f32m = *flag;
  int g = blockIdx.x * 256 + threadIdx.x;
  int row = g >> 4, l = g & 15;
  float sum = 0.f, sq = 0.f;
  if (f32m){
    const float* rp = (const float*)inp + row * 256 + l * 16;
    #pragma unroll
    for (int i = 0; i < 4; i++){
      float4 v = ((const float4*)rp)[i];
      sum += v.x + v.y + v.z + v.w;
      sq = fmaf(v.x, v.x, sq); sq = fmaf(v.y, v.y, sq);
      sq = fmaf(v.z, v.z, sq); sq = fmaf(v.w, v.w, sq);
    }
  } else {
    const u16* rp = (const u16*)inp + row * 256 + l * 16;
    #pragma unroll
    for (int i = 0; i < 2; i++){
      uint4 u = ((const uint4*)rp)[i];
      unsigned w[4] = {u.x, u.y, u.z, u.w};
      #pragma unroll
      for (int p = 0; p < 4; p++){
        float a = bflo(w[p]), b = bfhi(w[p]);
        sum += a + b; sq = fmaf(a, a, sq); sq = fmaf(b, b, sq);
      }
    }
  }
  #pragma unroll
  for (int m = 1; m < 16; m <<= 1){ sum += __shfl_xor(sum, m); sq += __shfl_xor(sq, m); }
  if (l == 0){
    float mu = sum * (1.f/256.f);
    float var = sq * (1.f/256.f) - mu * mu;
    stats[row] = make_float2(mu, rsqrtf(var + 1e-5f));
  }
}

// ---------- K1: GEMM, stats precomputed; vT grouped [b][key/64][cv][key%64];
// vT stores are NON-TEMPORAL (streaming): write-once data, avoids pinning
// partially-dirty L2 lines (r8 showed WRITE 188->134 MB when concurrency halved;
// nt targets the same partial-line-eviction amplification without the occupancy cost).
__global__ __launch_bounds__(256) void k1_gemm(
    const void* __restrict__ inp, const int* __restrict__ flag,
    const float2* __restrict__ stats, const float* __restrict__ beta,
    const _Float16* __restrict__ wkvh, _Float16* __restrict__ kh, _Float16* __restrict__ vT)
{
  int f32m = *flag;
  int tid = threadIdx.x;
  int wv = tid >> 6, lane = tid & 63;
  int m16 = lane & 15, q4 = lane >> 4;
  int nb = blockIdx.y;
  long rowb0 = (long)blockIdx.x * 128;
  int colW = nb * 256 + wv * 64;                  // wave's base col

  half8 bfr[4][8];
  #pragma unroll
  for (int nt = 0; nt < 4; nt++)
    #pragma unroll
    for (int s = 0; s < 8; s++)
      bfr[nt][s] = *(const half8*)(wkvh + (colW + nt * 16 + m16) * 256 + s * 32 + q4 * 8);

  float bet[4];
  #pragma unroll
  for (int nt = 0; nt < 4; nt++) bet[nt] = beta[colW + nt * 16 + m16];

  for (int rt = 0; rt < 8; rt++){
    long rowb = rowb0 + rt * 16;
    long myRow = rowb + m16;
    float2 st = stats[myRow];
    float mu = st.x, rstd = st.y;

    half8 af[8];
    if (f32m){
      const float* rp = (const float*)inp + myRow * 256 + q4 * 8;
      #pragma unroll
      for (int s = 0; s < 8; s++){
        float4 x0 = *(const float4*)(rp + s * 32);
        float4 x1 = *(const float4*)(rp + s * 32 + 4);
        af[s][0] = (_Float16)((x0.x - mu) * rstd); af[s][1] = (_Float16)((x0.y - mu) * rstd);
        af[s][2] = (_Float16)((x0.z - mu) * rstd); af[s][3] = (_Float16)((x0.w - mu) * rstd);
        af[s][4] = (_Float16)((x1.x - mu) * rstd); af[s][5] = (_Float16)((x1.y - mu) * rstd);
        af[s][6] = (_Float16)((x1.z - mu) * rstd); af[s][7] = (_Float16)((x1.w - mu) * rstd);
      }
    } else {
      const u16* rp = (const u16*)inp + myRow * 256 + q4 * 8;
      #pragma unroll
      for (int s = 0; s < 8; s++){
        uint4 xu = *(const uint4*)(rp + s * 32);
        unsigned xw[4] = {xu.x, xu.y, xu.z, xu.w};
        #pragma unroll
        for (int p = 0; p < 4; p++){
          af[s][2*p]   = (_Float16)((bflo(xw[p]) - mu) * rstd);
          af[s][2*p+1] = (_Float16)((bfhi(xw[p]) - mu) * rstd);
        }
      }
    }

    floatx4 acc[4];
    #pragma unroll
    for (int nt = 0; nt < 4; nt++){
      acc[nt][0] = bet[nt]; acc[nt][1] = bet[nt]; acc[nt][2] = bet[nt]; acc[nt][3] = bet[nt];
    }
    #pragma unroll
    for (int s = 0; s < 8; s++)
      #pragma unroll
      for (int nt = 0; nt < 4; nt++)
        acc[nt] = __builtin_amdgcn_mfma_f32_16x16x32_f16(af[s], bfr[nt][s], acc[nt], 0, 0, 0);

    if (nb == 0){
      long crow = rowb + q4 * 4;
      #pragma unroll
      for (int nt = 0; nt < 4; nt++)
        #pragma unroll
        for (int r = 0; r < 4; r++)
          kh[(crow + r) * 256 + colW + nt * 16 + m16] = (_Float16)acc[nt][r];
    } else {
      int b = (int)(rowb >> 12);
      int key = ((int)rowb & 4095) + q4 * 4;
      int kg  = key >> 6;
      int klo = key & 63;
      #pragma unroll
      for (int nt = 0; nt < 4; nt++){
        int cv = (colW - 256) + nt * 16 + m16;
        half4 pk;
        pk[0] = (_Float16)acc[nt][0]; pk[1] = (_Float16)acc[nt][1];
        pk[2] = (_Float16)acc[nt][2]; pk[3] = (_Float16)acc[nt][3];
        unsigned long long uv;
        __builtin_memcpy(&uv, &pk, 8);
        __builtin_nontemporal_store(uv,
            (unsigned long long*)(vT + (((long)b * 64 + kg) * 256 + cv) * 64 + klo));
      }
    }
  }
}

// ---------- K2: slot LN + q projection (iter 0 only; zeroes denom) ----------
__global__ __launch_bounds__(256) void k2_q(
    const float* __restrict__ slots, const u16* __restrict__ cw, _Float16* __restrict__ qh,
    float* __restrict__ denom)
{
  const u16* gq = cw + CW_GS;
  const u16* bq = cw + CW_BS;
  const u16* Wq = cw + CW_WQ;
  int row = blockIdx.x, tid = threadIdx.x;
  if (row < 16) denom[row * 256 + tid] = 0.f;           // 4096
  int wv = tid >> 6, lane = tid & 63;
  float x = slots[row * 256 + tid];
  float s = x, s2 = x * x;
  #pragma unroll
  for (int m = 1; m < 64; m <<= 1){ s += __shfl_xor(s, m); s2 += __shfl_xor(s2, m); }
  __shared__ float red[8];
  if (lane == 0){ red[wv] = s; red[4 + wv] = s2; }
  __syncthreads();
  float tot  = red[0] + red[1] + red[2] + red[3];
  float tot2 = red[4] + red[5] + red[6] + red[7];
  float mu = tot * (1.f/256.f);
  float rstd = rsqrtf(tot2 * (1.f/256.f) - mu * mu + 1e-5f);
  __shared__ float sln[256];
  sln[tid] = (x - mu) * rstd * bf1(gq[tid]) + bf1(bq[tid]);
  __syncthreads();
  const u16* wr = Wq + tid * 256;
  float a = 0.f;
  for (int k = 0; k < 256; k += 8){
    uint4 wu = *(const uint4*)(wr + k);
    float4 l0 = *(const float4*)(sln + k);
    float4 l1 = *(const float4*)(sln + k + 4);
    a = dot8(wu, l0, l1, a);
  }
  qh[row * 256 + tid] = (_Float16)(a * 0.17677669529663687f);
}

// ---------- K3: logits(MFMA) + joint softmax + MFMA numer (r9 exact) ----------
// grid (32 batches fastest, 16 chunks). Wave w owns heads 2w,2w+1.
// 64 keys per phase group (4 groups/chunk); K prefetched; vT hoisted (T14).
// vT is in grouped layout [b][key/64][cv][key%64].
// Iters 0,1: f16 numer partials into d_out scratch (k_reduce consumes).
// Last iter: f32 atomic numer + direct attn_vis write from phase B.
__global__ __launch_bounds__(256) void k3_attn(
    const _Float16* __restrict__ kh, const _Float16* __restrict__ vT,
    const _Float16* __restrict__ qh,
    float* __restrict__ denom, float* __restrict__ numer,
    void* __restrict__ out_scratch, const int* __restrict__ flag, int lastIter)
{
  int f32m = *flag;
  int tid = threadIdx.x;
  int wv = tid >> 6, lane = tid & 63;
  int m16 = lane & 15, q4 = lane >> 4;
  int b = blockIdx.x, chunk = blockIdx.y;
  __shared__ float lds_l[64 * 129];               // [key 0..63][h*16+q]  (33 KB)

  half8 qf[2];
  #pragma unroll
  for (int hh = 0; hh < 2; hh++){
    int h = wv * 2 + hh;
    qf[hh] = *(const half8*)(qh + (b * 16 + m16) * 256 + h * 32 + q4 * 8);
  }
  float pd[2] = {0.f, 0.f};
  floatx4 un[2][2];
  #pragma unroll
  for (int hh = 0; hh < 2; hh++)
    #pragma unroll
    for (int dt = 0; dt < 2; dt++) un[hh][dt] = (floatx4)0.f;

  half8 afp[4][2];                                 // prefetched K fragments (64 keys)
  {
    int key0 = chunk * 256;
    #pragma unroll
    for (int sub = 0; sub < 4; sub++){
      long rowb = (long)b * 4096 + key0 + sub * 16;
      #pragma unroll
      for (int hh = 0; hh < 2; hh++)
        afp[sub][hh] = *(const half8*)(kh + (rowb + m16) * 256 + (wv * 2 + hh) * 32 + q4 * 8);
    }
  }

  floatx4 z4 = (floatx4)0.f;
  for (int grp = 0; grp < 4; grp++){
    int key0 = chunk * 256 + grp * 64;
    // phase A: logits for 64 keys x 2 heads per wave (from prefetched regs)
    #pragma unroll
    for (int sub = 0; sub < 4; sub++){
      #pragma unroll
      for (int hh = 0; hh < 2; hh++){
        int h = wv * 2 + hh;
        floatx4 d = __builtin_amdgcn_mfma_f32_16x16x32_f16(afp[sub][hh], qf[hh], z4, 0, 0, 0);
        #pragma unroll
        for (int r = 0; r < 4; r++)
          lds_l[(sub * 16 + q4 * 4 + r) * 129 + h * 16 + m16] = d[r];
      }
    }
    // issue next group's K loads; they drain during softmax + PV + barriers
    if (grp < 3){
      int keyn = key0 + 64;
      #pragma unroll
      for (int sub = 0; sub < 4; sub++){
        long rowb = (long)b * 4096 + keyn + sub * 16;
        #pragma unroll
        for (int hh = 0; hh < 2; hh++)
          afp[sub][hh] = *(const half8*)(kh + (rowb + m16) * 256 + (wv * 2 + hh) * 32 + q4 * 8);
      }
    }
    __syncthreads();
    // hoist phase-C vT loads (grouped layout) above softmax
    half8 vfr[2][2][2];                            // [ks][hh][dt]
    {
      int kg = key0 >> 6;
      #pragma unroll
      for (int ks = 0; ks < 2; ks++)
        #pragma unroll
        for (int hh = 0; hh < 2; hh++)
          #pragma unroll
          for (int dt = 0; dt < 2; dt++)
            vfr[ks][hh][dt] = *(const half8*)(vT +
                (((long)b * 64 + kg) * 256 + (wv * 2 + hh) * 32 + dt * 16 + m16) * 64
                + ks * 32 + q4 * 8);
    }
    // phase B: per-key joint softmax over 128 (h,q); each thread does 4 keys
    {
      int qq = tid & 15;
      #pragma unroll
      for (int half_ = 0; half_ < 4; half_++){
        int kk = (tid >> 4) + half_ * 16;
        float l[8];
        #pragma unroll
        for (int h8 = 0; h8 < 8; h8++) l[h8] = lds_l[kk * 129 + h8 * 16 + qq];
        float M = l[0];
        #pragma unroll
        for (int h8 = 1; h8 < 8; h8++) M = fmaxf(M, l[h8]);
        #pragma unroll
        for (int msk = 1; msk < 16; msk <<= 1) M = fmaxf(M, __shfl_xor(M, msk));
        float p[8], sl = 0.f;
        #pragma unroll
        for (int h8 = 0; h8 < 8; h8++){ p[h8] = __expf(l[h8] - M); sl += p[h8]; }
        float St = sl;
        #pragma unroll
        for (int msk = 1; msk < 16; msk <<= 1) St += __shfl_xor(St, msk);
        float rS = 1.f / St;
        if (lastIter){
          float av = sl * rS;                     // attn_vis = sum over heads
          long idx = 131072 + ((long)b * 4096 + key0 + kk) * 16 + qq;
          if (f32m) ((float*)out_scratch)[idx] = av;
          else      ((u16*)out_scratch)[idx]   = f2bf(av);
        }
        #pragma unroll
        for (int h8 = 0; h8 < 8; h8++) lds_l[kk * 129 + h8 * 16 + qq] = p[h8] * rS;
      }
    }
    __syncthreads();
    // phase C: U[d][q] += vT[d][key] * P[key][q] via MFMA over 64 keys
    #pragma unroll
    for (int hh = 0; hh < 2; hh++){
      int h = wv * 2 + hh;
      #pragma unroll
      for (int ks = 0; ks < 2; ks++){
        float pv[8];
        #pragma unroll
        for (int j = 0; j < 8; j++) pv[j] = lds_l[(ks * 32 + q4 * 8 + j) * 129 + h * 16 + m16];
        float ps = 0.f;
        #pragma unroll
        for (int j = 0; j < 8; j++) ps += pv[j];
        pd[hh] += ps;
        half8 bfr;
        #pragma unroll
        for (int j = 0; j < 8; j++) bfr[j] = (_Float16)pv[j];
        #pragma unroll
        for (int dt = 0; dt < 2; dt++)
          un[hh][dt] = __builtin_amdgcn_mfma_f32_16x16x32_f16(vfr[ks][hh][dt], bfr, un[hh][dt], 0, 0, 0);
      }
    }
    __syncthreads();
  }
  // denom always atomic (small); numer: partials (iters 0,1) or atomics (last)
  _Float16* pp = (_Float16*)((u16*)out_scratch + (f32m ? 262144 : 131072))
                 + (long)chunk * 131072;
  #pragma unroll
  for (int hh = 0; hh < 2; hh++){
    int h = wv * 2 + hh;
    float t = pd[hh];
    t += __shfl_xor(t, 16); t += __shfl_xor(t, 32);
    if (q4 == 0) atomicAdd(&denom[(b * 8 + h) * 16 + m16], t);
    if (lastIter){
      #pragma unroll
      for (int dt = 0; dt < 2; dt++)
        #pragma unroll
        for (int r = 0; r < 4; r++)
          atomicAdd(&numer[((b * 8 + h) * 16 + m16) * 32 + dt * 16 + q4 * 4 + r], un[hh][dt][r]);
    } else {
      #pragma unroll
      for (int dt = 0; dt < 2; dt++){
        half4 st;
        #pragma unroll
        for (int r = 0; r < 4; r++) st[r] = (_Float16)un[hh][dt][r];
        *(half4*)(pp + ((b * 8 + h) * 16 + m16) * 32 + dt * 16 + q4 * 4) = st;
      }
    }
  }
}

// ---------- reduce fp16 numer partials (16 chunks) -> f32 numer ----------
__global__ void k_reduce(const void* __restrict__ out_scratch, const int* __restrict__ flag,
                         float* __restrict__ numer){
  int i = blockIdx.x * 256 + threadIdx.x;        // 0..131071
  int f32m = *flag;
  const _Float16* pp = (const _Float16*)((const u16*)out_scratch + (f32m ? 262144 : 131072));
  float s = 0.f;
  #pragma unroll
  for (int c = 0; c < 16; c++) s += (float)pp[(long)c * 131072 + i];
  numer[i] = s;
}

// ---------- K4a: GRU cell -> mid (f32)  (r9 exact) ----------
__global__ __launch_bounds__(256) void k4a_gru(
    const float* __restrict__ slots, const float* __restrict__ numer, const float* __restrict__ denom,
    const u16* __restrict__ cw, float* __restrict__ mid)
{
  const u16* wih = cw + CW_WIH;
  const u16* whh = cw + CW_WHH;
  const u16* bih = cw + CW_BIH;
  const u16* bhh = cw + CW_BHH;
  int jc = blockIdx.x, rg = blockIdx.y;
  int tid = threadIdx.x;
  __shared__ float u_s[8][256];
  __shared__ float h_s[8][256];
  {
    int hh = tid >> 5, dh = tid & 31;
    for (int i = 0; i < 8; i++){
      int row = rg * 8 + i;
      int b = row >> 4, slot = row & 15;
      float den = denom[(b * 8 + hh) * 16 + slot] + 1e-8f;
      u_s[i][tid] = numer[((b * 8 + hh) * 16 + slot) * 32 + dh] / den;
      h_s[i][tid] = slots[row * 256 + tid];
    }
  }
  __syncthreads();
  int rl = tid >> 5, jl = tid & 31;
  int j = jc * 32 + jl;
  int row = rg * 8 + rl;
  const u16* wir = wih + j * 256;
  const u16* wiz = wih + (256 + j) * 256;
  const u16* win = wih + (512 + j) * 256;
  const u16* whr = whh + j * 256;
  const u16* whz = whh + (256 + j) * 256;
  const u16* whn = whh + (512 + j) * 256;
  float air = 0, aiz = 0, ain = 0, ahr = 0, ahz = 0, ahn = 0;
  for (int k = 0; k < 256; k += 8){
    float4 u0 = *(const float4*)(&u_s[rl][k]);
    float4 u1 = *(const float4*)(&u_s[rl][k + 4]);
    float4 h0 = *(const float4*)(&h_s[rl][k]);
    float4 h1 = *(const float4*)(&h_s[rl][k + 4]);
    air = dot8(*(const uint4*)(wir + k), u0, u1, air);
    aiz = dot8(*(const uint4*)(wiz + k), u0, u1, aiz);
    ain = dot8(*(const uint4*)(win + k), u0, u1, ain);
    ahr = dot8(*(const uint4*)(whr + k), h0, h1, ahr);
    ahz = dot8(*(const uint4*)(whz + k), h0, h1, ahz);
    ahn = dot8(*(const uint4*)(whn + k), h0, h1, ahn);
  }
  float gr = air + bf1(bih[j])       + ahr + bf1(bhh[j]);
  float gz = aiz + bf1(bih[256 + j]) + ahz + bf1(bhh[256 + j]);
  float r = 1.f / (1.f + __expf(-gr));
  float z = 1.f / (1.f + __expf(-gz));
  float nn = tanhf(ain + bf1(bih[512 + j]) + r * (ahn + bf1(bhh[512 + j])));
  float h = h_s[rl][j];
  mid[row * 256 + j] = (1.f - z) * nn + z * h;
}

// ---------- K4b: LN + MLP + residual; non-last iters fuse next iter's k2
// (LN(res; gs,bs) -> qh) + next iter's denom/numer zeroing ----------
__global__ __launch_bounds__(256) void k4b_mlp(
    const float* __restrict__ mid, const u16* __restrict__ cw,
    float* __restrict__ slots, void* __restrict__ out_base,
    const int* __restrict__ flag, int lastIter,
    _Float16* __restrict__ qh, float* __restrict__ denom, float* __restrict__ numer,
    int zeroNumer)
{
  int f32m = *flag;
  const u16* gm = cw + CW_GM;
  const u16* bm = cw + CW_BM;
  const u16* w1 = cw + CW_W1;
  const u16* b1 = cw + CW_B1;
  const u16* w2 = cw + CW_W2;
  const u16* b2 = cw + CW_B2;
  int row = blockIdx.x, tid = threadIdx.x;
  int wv = tid >> 6, lane = tid & 63;
  float x = mid[row * 256 + tid];
  float s = x, s2 = x * x;
  #pragma unroll
  for (int m = 1; m < 64; m <<= 1){ s += __shfl_xor(s, m); s2 += __shfl_xor(s2, m); }
  __shared__ float red[8];
  if (lane == 0){ red[wv] = s; red[4 + wv] = s2; }
  __syncthreads();
  float tot  = red[0] + red[1] + red[2] + red[3];
  float tot2 = red[4] + red[5] + red[6] + red[7];
  float mu = tot * (1.f/256.f);
  float rstd = rsqrtf(tot2 * (1.f/256.f) - mu * mu + 1e-5f);
  __shared__ float ls[256];
  __shared__ float h1[512];
  ls[tid] = (x - mu) * rstd * bf1(gm[tid]) + bf1(bm[tid]);
  __syncthreads();
  const u16* w1a = w1 + tid * 256;
  const u16* w1b = w1 + (tid + 256) * 256;
  float a0 = 0.f, a1 = 0.f;
  for (int k = 0; k < 256; k += 8){
    float4 l0 = *(const float4*)(ls + k);
    float4 l1 = *(const float4*)(ls + k + 4);
    a0 = dot8(*(const uint4*)(w1a + k), l0, l1, a0);
    a1 = dot8(*(const uint4*)(w1b + k), l0, l1, a1);
  }
  h1[tid]       = fmaxf(a0 + bf1(b1[tid]), 0.f);
  h1[tid + 256] = fmaxf(a1 + bf1(b1[tid + 256]), 0.f);
  __syncthreads();
  const u16* w2r = w2 + tid * 512;
  float a = 0.f;
  for (int k = 0; k < 512; k += 8){
    float4 l0 = *(const float4*)(h1 + k);
    float4 l1 = *(const float4*)(h1 + k + 4);
    a = dot8(*(const uint4*)(w2r + k), l0, l1, a);
  }
  float res = x + a + bf1(b2[tid]);
  slots[row * 256 + tid] = res;
  if (lastIter){
    int idx = row * 256 + tid;
    if (f32m) ((float*)out_base)[idx] = res;
    else      ((u16*)out_base)[idx]   = f2bf(res);
  } else {
    // ---- fused next-iter k2: LN(res; gs,bs) -> qh = (Wq · sln) * scale ----
    // plus next iter's zeroing (k4a of this iter already consumed denom/numer)
    if (zeroNumer) numer[row * 256 + tid] = 0.f;   // 512*256 = 131072 exactly
    if (row < 16) denom[row * 256 + tid] = 0.f;    // 4096
    float s3 = res, s4 = res * res;
    #pragma unroll
    for (int m = 1; m < 64; m <<= 1){ s3 += __shfl_xor(s3, m); s4 += __shfl_xor(s4, m); }
    __syncthreads();                               // h1/ls reads done; reuse red
    if (lane == 0){ red[wv] = s3; red[4 + wv] = s4; }
    __syncthreads();
    float t1 = red[0] + red[1] + red[2] + red[3];
    float t2 = red[4] + red[5] + red[6] + red[7];
    float mu2 = t1 * (1.f/256.f);
    float rs2 = rsqrtf(t2 * (1.f/256.f) - mu2 * mu2 + 1e-5f);
    ls[tid] = (res - mu2) * rs2 * bf1(cw[CW_GS + tid]) + bf1(cw[CW_BS + tid]);
    __syncthreads();
    const u16* wr = cw + CW_WQ + tid * 256;
    float aq = 0.f;
    for (int k = 0; k < 256; k += 8){
      uint4 wu = *(const uint4*)(wr + k);
      float4 l0 = *(const float4*)(ls + k);
      float4 l1 = *(const float4*)(ls + k + 4);
      aq = dot8(wu, l0, l1, aq);
    }
    qh[row * 256 + tid] = (_Float16)(aq * 0.17677669529663687f);
  }
}

// ---------- launch ----------
extern "C" void kernel_launch(void* const* d_in, const int* in_sizes, int n_in,
                              void* d_out, int out_size, void* d_ws, size_t ws_size,
                              hipStream_t stream)
{
  char* ws = (char*)d_ws;
  int*  flagp    = (int*)ws;                        // [0,256)
  u16*  cw       = (u16*)(ws + 256);                // 1719808 -> 1720064
  _Float16* qh   = (_Float16*)(ws + 1720064);       //  262144 -> 1982208
  _Float16* wkvh = (_Float16*)(ws + 1982208);       //  262144 -> 2244352
  float* slots   = (float*)(ws + 2244352);          //  524288 -> 2768640
  float* mid     = (float*)(ws + 2768640);          //  524288 -> 3292928
  float* numer   = (float*)(ws + 3292928);          //  524288 -> 3817216
  float* denom   = (float*)(ws + 3817216);          //   16384 -> 3833600
  _Float16* kh   = (_Float16*)(ws + 3833600);       // 67108864 -> 70942464
  _Float16* vT   = (_Float16*)(ws + 70942464);      // 67108864 -> 138051328
  // aliases (dead before the iteration loop):
  float2* stats  = (float2*)(ws + 2768640);         // 1 MB over mid+numer
  float*  beta   = (float*)(ws + 3817216);          // 2 KB in denom region

  CanonArgs ca;
  ca.p[0]  = d_in[0];   ca.p[1]  = d_in[2];   ca.p[2]  = d_in[3];
  ca.p[3]  = d_in[4];   ca.p[4]  = d_in[5];   ca.p[5]  = d_in[6];
  ca.p[6]  = d_in[7];   ca.p[7]  = d_in[8];   ca.p[8]  = d_in[9];
  ca.p[9]  = d_in[10];  ca.p[10] = d_in[11];  ca.p[11] = d_in[12];
  ca.p[12] = d_in[13];  ca.p[13] = d_in[14];  ca.p[14] = d_in[15];
  ca.p[15] = d_in[16];  ca.p[16] = d_in[17];  ca.p[17] = d_in[18];

  k_flag<<<1, 256, 0, stream>>>((const u16*)d_in[1], flagp);
  k_canon<<<(CW_TOTAL + 255) / 256, 256, 0, stream>>>(ca, flagp, cw);
  k_init<<<1024, 256, 0, stream>>>(cw, slots, wkvh);
  k_beta<<<2, 256, 0, stream>>>(cw, beta);
  k0_stats<<<8192, 256, 0, stream>>>(d_in[1], flagp, stats);
  k1_gemm<<<dim3(1024, 2), 256, 0, stream>>>(d_in[1], flagp, stats, beta, wkvh, kh, vT);
  // iter 0's qh + denom zeroing (k4b handles subsequent iters)
  k2_q<<<512, 256, 0, stream>>>(slots, cw, qh, denom);
  for (int it = 0; it < 3; it++){
    int last = (it == 2) ? 1 : 0;
    k3_attn<<<dim3(32, 16), 256, 0, stream>>>(kh, vT, qh, denom, numer, d_out, flagp, last);
    if (!last) k_reduce<<<512, 256, 0, stream>>>(d_out, flagp, numer);
    k4a_gru<<<dim3(8, 64), 256, 0, stream>>>(slots, numer, denom, cw, mid);
    k4b_mlp<<<512, 256, 0, stream>>>(mid, cw, slots, d_out, flagp, last,
                                     qh, denom, numer, (it == 1) ? 1 : 0);
  }
}

// Round 15
// 787.601 us; speedup vs baseline: 1.0006x; 1.0006x over previous
//
#include <hip/hip_runtime.h>
#include <stdint.h>

typedef unsigned short u16;
typedef __attribute__((ext_vector_type(8))) _Float16 half8;
typedef __attribute__((ext_vector_type(4))) _Float16 half4;
typedef __attribute__((ext_vector_type(4))) float floatx4;

// ---------- helpers ----------
__device__ inline float bflo(unsigned u){ return __uint_as_float(u << 16); }
__device__ inline float bfhi(unsigned u){ return __uint_as_float(u & 0xffff0000u); }
__device__ inline float bf1(u16 v){ return __uint_as_float(((unsigned)v) << 16); }
__device__ inline u16 f2bf(float f){
  unsigned u = __float_as_uint(f);
  u += 0x7fffu + ((u >> 16) & 1u);           // RNE
  return (u16)(u >> 16);
}
__device__ inline float dot8(uint4 w, float4 a, float4 b, float acc){
  acc = fmaf(bflo(w.x), a.x, acc); acc = fmaf(bfhi(w.x), a.y, acc);
  acc = fmaf(bflo(w.y), a.z, acc); acc = fmaf(bfhi(w.y), a.w, acc);
  acc = fmaf(bflo(w.z), b.x, acc); acc = fmaf(bfhi(w.z), b.y, acc);
  acc = fmaf(bflo(w.w), b.z, acc); acc = fmaf(bfhi(w.w), b.w, acc);
  return acc;
}

// canonical weight buffer offsets (u16 elements), d_in order (skipping inputs)
#define CW_SLOTS 0
#define CW_GIN   4096
#define CW_BIN   4352
#define CW_GS    4608
#define CW_BS    4864
#define CW_GM    5120
#define CW_BM    5376
#define CW_WQ    5632
#define CW_WK    71168
#define CW_WV    136704
#define CW_WIH   202240
#define CW_WHH   398848
#define CW_BIH   595456
#define CW_BHH   596224
#define CW_W1    596992
#define CW_B1    728064
#define CW_W2    728576
#define CW_B2    859648
#define CW_TOTAL 859904

// ---------- dtype probe ----------
__global__ void k_flag(const u16* __restrict__ probe, int* __restrict__ flag){
  int t = threadIdx.x;
  int bad = 0;
  #pragma unroll
  for (int i = 0; i < 4; i++){
    float x = bf1(probe[t + i * 256]);
    if (!(fabsf(x) < 1e6f)) bad = 1;
  }
  __shared__ int s;
  if (t == 0) s = 0;
  __syncthreads();
  if (bad) atomicOr(&s, 1);
  __syncthreads();
  if (t == 0) *flag = s;
}

// ---------- canonicalize all weight/bias arrays to bf16 in ws ----------
struct CanonArgs { const void* p[18]; };

__global__ void k_canon(CanonArgs a, const int* __restrict__ flag, u16* __restrict__ cw){
  const int off[19] = {CW_SLOTS, CW_GIN, CW_BIN, CW_GS, CW_BS, CW_GM, CW_BM, CW_WQ,
                       CW_WK, CW_WV, CW_WIH, CW_WHH, CW_BIH, CW_BHH, CW_W1, CW_B1,
                       CW_W2, CW_B2, CW_TOTAL};
  int i = blockIdx.x * 256 + threadIdx.x;
  if (i >= CW_TOTAL) return;
  int f32m = *flag;
  int j = 0;
  while (i >= off[j + 1]) j++;
  int local = i - off[j];
  float v = f32m ? ((const float*)a.p[j])[local] : bf1(((const u16*)a.p[j])[local]);
  cw[i] = f2bf(v);
}

// ---------- init: wkvh[c][d] = Wkv[c][d]*gin[d] (fp16); broadcast slots -> f32 ----------
__global__ void k_init(const u16* __restrict__ cw, float* __restrict__ slots,
                       _Float16* __restrict__ wkvh)
{
  int idx = blockIdx.x * 256 + threadIdx.x;      // 0..262143
  if (idx < 131072){
    float g = bf1(cw[CW_GIN + (idx & 255)]);
    wkvh[idx] = (_Float16)(bf1(cw[CW_WK + idx]) * g);   // Wk|Wv contiguous
  } else {
    int i = idx - 131072;
    int d = i & 255;
    int q = (i >> 8) & 15;
    slots[i] = bf1(cw[CW_SLOTS + q * 256 + d]);
  }
}

// beta[c] = sum_d bin[d] * Wkv[c][d]  (512 cols)
__global__ void k_beta(const u16* __restrict__ cw, float* __restrict__ beta){
  int c = blockIdx.x * 256 + threadIdx.x;
  if (c >= 512) return;
  float a = 0.f;
  for (int d = 0; d < 256; d++)
    a = fmaf(bf1(cw[CW_BIN + d]), bf1(cw[CW_WK + c * 256 + d]), a);
  beta[c] = a;
}

// ---------- K0: per-row LN stats (mu, rstd); 16 lanes per row ----------
__global__ __launch_bounds__(256) void k0_stats(
    const void* __restrict__ inp, const int* __restrict__ flag, float2* __restrict__ stats)
{
  int f32m = *flag;
  int g = blockIdx.x * 256 + threadIdx.x;
  int row = g >> 4, l = g & 15;
  float sum = 0.f, sq = 0.f;
  if (f32m){
    const float* rp = (const float*)inp + row * 256 + l * 16;
    #pragma unroll
    for (int i = 0; i < 4; i++){
      float4 v = ((const float4*)rp)[i];
      sum += v.x + v.y + v.z + v.w;
      sq = fmaf(v.x, v.x, sq); sq = fmaf(v.y, v.y, sq);
      sq = fmaf(v.z, v.z, sq); sq = fmaf(v.w, v.w, sq);
    }
  } else {
    const u16* rp = (const u16*)inp + row * 256 + l * 16;
    #pragma unroll
    for (int i = 0; i < 2; i++){
      uint4 u = ((const uint4*)rp)[i];
      unsigned w[4] = {u.x, u.y, u.z, u.w};
      #pragma unroll
      for (int p = 0; p < 4; p++){
        float a = bflo(w[p]), b = bfhi(w[p]);
        sum += a + b; sq = fmaf(a, a, sq); sq = fmaf(b, b, sq);
      }
    }
  }
  #pragma unroll
  for (int m = 1; m < 16; m <<= 1){ sum += __shfl_xor(sum, m); sq += __shfl_xor(sq, m); }
  if (l == 0){
    float mu = sum * (1.f/256.f);
    float var = sq * (1.f/256.f) - mu * mu;
    stats[row] = make_float2(mu, rsqrtf(var + 1e-5f));
  }
}

// ---------- K1: GEMM, 512-thread blocks covering ALL 512 cols ----------
// waves 0-3 -> kh cols 0..255; waves 4-7 -> vT cols 0..255 (colW = wv*64).
// Input rows read ONCE per block: FETCH 135 -> ~68 MB (r14 proved writes are
// already ideal via nt stores; this removes the duplicate input read).
// Per-wave body identical to r0/r9; vT grouped [b][key/64][cv][key%64] + nt.
__global__ __launch_bounds__(512) void k1_gemm(
    const void* __restrict__ inp, const int* __restrict__ flag,
    const float2* __restrict__ stats, const float* __restrict__ beta,
    const _Float16* __restrict__ wkvh, _Float16* __restrict__ kh, _Float16* __restrict__ vT)
{
  int f32m = *flag;
  int tid = threadIdx.x;
  int wv = tid >> 6, lane = tid & 63;
  int m16 = lane & 15, q4 = lane >> 4;
  int nb = wv >> 2;                                // 0: kh-half, 1: vT-half
  long rowb0 = (long)blockIdx.x * 128;
  int colW = wv * 64;                              // wave's base col (0..448)

  half8 bfr[4][8];
  #pragma unroll
  for (int nt = 0; nt < 4; nt++)
    #pragma unroll
    for (int s = 0; s < 8; s++)
      bfr[nt][s] = *(const half8*)(wkvh + (colW + nt * 16 + m16) * 256 + s * 32 + q4 * 8);

  float bet[4];
  #pragma unroll
  for (int nt = 0; nt < 4; nt++) bet[nt] = beta[colW + nt * 16 + m16];

  for (int rt = 0; rt < 8; rt++){
    long rowb = rowb0 + rt * 16;
    long myRow = rowb + m16;
    float2 st = stats[myRow];
    float mu = st.x, rstd = st.y;

    half8 af[8];
    if (f32m){
      const float* rp = (const float*)inp + myRow * 256 + q4 * 8;
      #pragma unroll
      for (int s = 0; s < 8; s++){
        float4 x0 = *(const float4*)(rp + s * 32);
        float4 x1 = *(const float4*)(rp + s * 32 + 4);
        af[s][0] = (_Float16)((x0.x - mu) * rstd); af[s][1] = (_Float16)((x0.y - mu) * rstd);
        af[s][2] = (_Float16)((x0.z - mu) * rstd); af[s][3] = (_Float16)((x0.w - mu) * rstd);
        af[s][4] = (_Float16)((x1.x - mu) * rstd); af[s][5] = (_Float16)((x1.y - mu) * rstd);
        af[s][6] = (_Float16)((x1.z - mu) * rstd); af[s][7] = (_Float16)((x1.w - mu) * rstd);
      }
    } else {
      const u16* rp = (const u16*)inp + myRow * 256 + q4 * 8;
      #pragma unroll
      for (int s = 0; s < 8; s++){
        uint4 xu = *(const uint4*)(rp + s * 32);
        unsigned xw[4] = {xu.x, xu.y, xu.z, xu.w};
        #pragma unroll
        for (int p = 0; p < 4; p++){
          af[s][2*p]   = (_Float16)((bflo(xw[p]) - mu) * rstd);
          af[s][2*p+1] = (_Float16)((bfhi(xw[p]) - mu) * rstd);
        }
      }
    }

    floatx4 acc[4];
    #pragma unroll
    for (int nt = 0; nt < 4; nt++){
      acc[nt][0] = bet[nt]; acc[nt][1] = bet[nt]; acc[nt][2] = bet[nt]; acc[nt][3] = bet[nt];
    }
    #pragma unroll
    for (int s = 0; s < 8; s++)
      #pragma unroll
      for (int nt = 0; nt < 4; nt++)
        acc[nt] = __builtin_amdgcn_mfma_f32_16x16x32_f16(af[s], bfr[nt][s], acc[nt], 0, 0, 0);

    if (nb == 0){
      long crow = rowb + q4 * 4;
      #pragma unroll
      for (int nt = 0; nt < 4; nt++)
        #pragma unroll
        for (int r = 0; r < 4; r++)
          kh[(crow + r) * 256 + colW + nt * 16 + m16] = (_Float16)acc[nt][r];
    } else {
      int b = (int)(rowb >> 12);
      int key = ((int)rowb & 4095) + q4 * 4;
      int kg  = key >> 6;
      int klo = key & 63;
      #pragma unroll
      for (int nt = 0; nt < 4; nt++){
        int cv = (colW - 256) + nt * 16 + m16;
        half4 pk;
        pk[0] = (_Float16)acc[nt][0]; pk[1] = (_Float16)acc[nt][1];
        pk[2] = (_Float16)acc[nt][2]; pk[3] = (_Float16)acc[nt][3];
        unsigned long long uv;
        __builtin_memcpy(&uv, &pk, 8);
        __builtin_nontemporal_store(uv,
            (unsigned long long*)(vT + (((long)b * 64 + kg) * 256 + cv) * 64 + klo));
      }
    }
  }
}

// ---------- K2: slot LN + q projection (iter 0 only; zeroes denom) ----------
__global__ __launch_bounds__(256) void k2_q(
    const float* __restrict__ slots, const u16* __restrict__ cw, _Float16* __restrict__ qh,
    float* __restrict__ denom)
{
  const u16* gq = cw + CW_GS;
  const u16* bq = cw + CW_BS;
  const u16* Wq = cw + CW_WQ;
  int row = blockIdx.x, tid = threadIdx.x;
  if (row < 16) denom[row * 256 + tid] = 0.f;           // 4096
  int wv = tid >> 6, lane = tid & 63;
  float x = slots[row * 256 + tid];
  float s = x, s2 = x * x;
  #pragma unroll
  for (int m = 1; m < 64; m <<= 1){ s += __shfl_xor(s, m); s2 += __shfl_xor(s2, m); }
  __shared__ float red[8];
  if (lane == 0){ red[wv] = s; red[4 + wv] = s2; }
  __syncthreads();
  float tot  = red[0] + red[1] + red[2] + red[3];
  float tot2 = red[4] + red[5] + red[6] + red[7];
  float mu = tot * (1.f/256.f);
  float rstd = rsqrtf(tot2 * (1.f/256.f) - mu * mu + 1e-5f);
  __shared__ float sln[256];
  sln[tid] = (x - mu) * rstd * bf1(gq[tid]) + bf1(bq[tid]);
  __syncthreads();
  const u16* wr = Wq + tid * 256;
  float a = 0.f;
  for (int k = 0; k < 256; k += 8){
    uint4 wu = *(const uint4*)(wr + k);
    float4 l0 = *(const float4*)(sln + k);
    float4 l1 = *(const float4*)(sln + k + 4);
    a = dot8(wu, l0, l1, a);
  }
  qh[row * 256 + tid] = (_Float16)(a * 0.17677669529663687f);
}

// ---------- K3: logits(MFMA) + joint softmax + MFMA numer (r9 exact) ----------
// grid (32 batches fastest, 16 chunks). Wave w owns heads 2w,2w+1.
// 64 keys per phase group (4 groups/chunk); K prefetched; vT hoisted (T14).
// vT is in grouped layout [b][key/64][cv][key%64].
// Iters 0,1: f16 numer partials into d_out scratch (k_reduce consumes).
// Last iter: f32 atomic numer + direct attn_vis write from phase B.
__global__ __launch_bounds__(256) void k3_attn(
    const _Float16* __restrict__ kh, const _Float16* __restrict__ vT,
    const _Float16* __restrict__ qh,
    float* __restrict__ denom, float* __restrict__ numer,
    void* __restrict__ out_scratch, const int* __restrict__ flag, int lastIter)
{
  int f32m = *flag;
  int tid = threadIdx.x;
  int wv = tid >> 6, lane = tid & 63;
  int m16 = lane & 15, q4 = lane >> 4;
  int b = blockIdx.x, chunk = blockIdx.y;
  __shared__ float lds_l[64 * 129];               // [key 0..63][h*16+q]  (33 KB)

  half8 qf[2];
  #pragma unroll
  for (int hh = 0; hh < 2; hh++){
    int h = wv * 2 + hh;
    qf[hh] = *(const half8*)(qh + (b * 16 + m16) * 256 + h * 32 + q4 * 8);
  }
  float pd[2] = {0.f, 0.f};
  floatx4 un[2][2];
  #pragma unroll
  for (int hh = 0; hh < 2; hh++)
    #pragma unroll
    for (int dt = 0; dt < 2; dt++) un[hh][dt] = (floatx4)0.f;

  half8 afp[4][2];                                 // prefetched K fragments (64 keys)
  {
    int key0 = chunk * 256;
    #pragma unroll
    for (int sub = 0; sub < 4; sub++){
      long rowb = (long)b * 4096 + key0 + sub * 16;
      #pragma unroll
      for (int hh = 0; hh < 2; hh++)
        afp[sub][hh] = *(const half8*)(kh + (rowb + m16) * 256 + (wv * 2 + hh) * 32 + q4 * 8);
    }
  }

  floatx4 z4 = (floatx4)0.f;
  for (int grp = 0; grp < 4; grp++){
    int key0 = chunk * 256 + grp * 64;
    // phase A: logits for 64 keys x 2 heads per wave (from prefetched regs)
    #pragma unroll
    for (int sub = 0; sub < 4; sub++){
      #pragma unroll
      for (int hh = 0; hh < 2; hh++){
        int h = wv * 2 + hh;
        floatx4 d = __builtin_amdgcn_mfma_f32_16x16x32_f16(afp[sub][hh], qf[hh], z4, 0, 0, 0);
        #pragma unroll
        for (int r = 0; r < 4; r++)
          lds_l[(sub * 16 + q4 * 4 + r) * 129 + h * 16 + m16] = d[r];
      }
    }
    // issue next group's K loads; they drain during softmax + PV + barriers
    if (grp < 3){
      int keyn = key0 + 64;
      #pragma unroll
      for (int sub = 0; sub < 4; sub++){
        long rowb = (long)b * 4096 + keyn + sub * 16;
        #pragma unroll
        for (int hh = 0; hh < 2; hh++)
          afp[sub][hh] = *(const half8*)(kh + (rowb + m16) * 256 + (wv * 2 + hh) * 32 + q4 * 8);
      }
    }
    __syncthreads();
    // hoist phase-C vT loads (grouped layout) above softmax
    half8 vfr[2][2][2];                            // [ks][hh][dt]
    {
      int kg = key0 >> 6;
      #pragma unroll
      for (int ks = 0; ks < 2; ks++)
        #pragma unroll
        for (int hh = 0; hh < 2; hh++)
          #pragma unroll
          for (int dt = 0; dt < 2; dt++)
            vfr[ks][hh][dt] = *(const half8*)(vT +
                (((long)b * 64 + kg) * 256 + (wv * 2 + hh) * 32 + dt * 16 + m16) * 64
                + ks * 32 + q4 * 8);
    }
    // phase B: per-key joint softmax over 128 (h,q); each thread does 4 keys
    {
      int qq = tid & 15;
      #pragma unroll
      for (int half_ = 0; half_ < 4; half_++){
        int kk = (tid >> 4) + half_ * 16;
        float l[8];
        #pragma unroll
        for (int h8 = 0; h8 < 8; h8++) l[h8] = lds_l[kk * 129 + h8 * 16 + qq];
        float M = l[0];
        #pragma unroll
        for (int h8 = 1; h8 < 8; h8++) M = fmaxf(M, l[h8]);
        #pragma unroll
        for (int msk = 1; msk < 16; msk <<= 1) M = fmaxf(M, __shfl_xor(M, msk));
        float p[8], sl = 0.f;
        #pragma unroll
        for (int h8 = 0; h8 < 8; h8++){ p[h8] = __expf(l[h8] - M); sl += p[h8]; }
        float St = sl;
        #pragma unroll
        for (int msk = 1; msk < 16; msk <<= 1) St += __shfl_xor(St, msk);
        float rS = 1.f / St;
        if (lastIter){
          float av = sl * rS;                     // attn_vis = sum over heads
          long idx = 131072 + ((long)b * 4096 + key0 + kk) * 16 + qq;
          if (f32m) ((float*)out_scratch)[idx] = av;
          else      ((u16*)out_scratch)[idx]   = f2bf(av);
        }
        #pragma unroll
        for (int h8 = 0; h8 < 8; h8++) lds_l[kk * 129 + h8 * 16 + qq] = p[h8] * rS;
      }
    }
    __syncthreads();
    // phase C: U[d][q] += vT[d][key] * P[key][q] via MFMA over 64 keys
    #pragma unroll
    for (int hh = 0; hh < 2; hh++){
      int h = wv * 2 + hh;
      #pragma unroll
      for (int ks = 0; ks < 2; ks++){
        float pv[8];
        #pragma unroll
        for (int j = 0; j < 8; j++) pv[j] = lds_l[(ks * 32 + q4 * 8 + j) * 129 + h * 16 + m16];
        float ps = 0.f;
        #pragma unroll
        for (int j = 0; j < 8; j++) ps += pv[j];
        pd[hh] += ps;
        half8 bfr;
        #pragma unroll
        for (int j = 0; j < 8; j++) bfr[j] = (_Float16)pv[j];
        #pragma unroll
        for (int dt = 0; dt < 2; dt++)
          un[hh][dt] = __builtin_amdgcn_mfma_f32_16x16x32_f16(vfr[ks][hh][dt], bfr, un[hh][dt], 0, 0, 0);
      }
    }
    __syncthreads();
  }
  // denom always atomic (small); numer: partials (iters 0,1) or atomics (last)
  _Float16* pp = (_Float16*)((u16*)out_scratch + (f32m ? 262144 : 131072))
                 + (long)chunk * 131072;
  #pragma unroll
  for (int hh = 0; hh < 2; hh++){
    int h = wv * 2 + hh;
    float t = pd[hh];
    t += __shfl_xor(t, 16); t += __shfl_xor(t, 32);
    if (q4 == 0) atomicAdd(&denom[(b * 8 + h) * 16 + m16], t);
    if (lastIter){
      #pragma unroll
      for (int dt = 0; dt < 2; dt++)
        #pragma unroll
        for (int r = 0; r < 4; r++)
          atomicAdd(&numer[((b * 8 + h) * 16 + m16) * 32 + dt * 16 + q4 * 4 + r], un[hh][dt][r]);
    } else {
      #pragma unroll
      for (int dt = 0; dt < 2; dt++){
        half4 st;
        #pragma unroll
        for (int r = 0; r < 4; r++) st[r] = (_Float16)un[hh][dt][r];
        *(half4*)(pp + ((b * 8 + h) * 16 + m16) * 32 + dt * 16 + q4 * 4) = st;
      }
    }
  }
}

// ---------- reduce fp16 numer partials (16 chunks) -> f32 numer ----------
__global__ void k_reduce(const void* __restrict__ out_scratch, const int* __restrict__ flag,
                         float* __restrict__ numer){
  int i = blockIdx.x * 256 + threadIdx.x;        // 0..131071
  int f32m = *flag;
  const _Float16* pp = (const _Float16*)((const u16*)out_scratch + (f32m ? 262144 : 131072));
  float s = 0.f;
  #pragma unroll
  for (int c = 0; c < 16; c++) s += (float)pp[(long)c * 131072 + i];
  numer[i] = s;
}

// ---------- K4a: GRU cell -> mid (f32)  (r9 exact) ----------
__global__ __launch_bounds__(256) void k4a_gru(
    const float* __restrict__ slots, const float* __restrict__ numer, const float* __restrict__ denom,
    const u16* __restrict__ cw, float* __restrict__ mid)
{
  const u16* wih = cw + CW_WIH;
  const u16* whh = cw + CW_WHH;
  const u16* bih = cw + CW_BIH;
  const u16* bhh = cw + CW_BHH;
  int jc = blockIdx.x, rg = blockIdx.y;
  int tid = threadIdx.x;
  __shared__ float u_s[8][256];
  __shared__ float h_s[8][256];
  {
    int hh = tid >> 5, dh = tid & 31;
    for (int i = 0; i < 8; i++){
      int row = rg * 8 + i;
      int b = row >> 4, slot = row & 15;
      float den = denom[(b * 8 + hh) * 16 + slot] + 1e-8f;
      u_s[i][tid] = numer[((b * 8 + hh) * 16 + slot) * 32 + dh] / den;
      h_s[i][tid] = slots[row * 256 + tid];
    }
  }
  __syncthreads();
  int rl = tid >> 5, jl = tid & 31;
  int j = jc * 32 + jl;
  int row = rg * 8 + rl;
  const u16* wir = wih + j * 256;
  const u16* wiz = wih + (256 + j) * 256;
  const u16* win = wih + (512 + j) * 256;
  const u16* whr = whh + j * 256;
  const u16* whz = whh + (256 + j) * 256;
  const u16* whn = whh + (512 + j) * 256;
  float air = 0, aiz = 0, ain = 0, ahr = 0, ahz = 0, ahn = 0;
  for (int k = 0; k < 256; k += 8){
    float4 u0 = *(const float4*)(&u_s[rl][k]);
    float4 u1 = *(const float4*)(&u_s[rl][k + 4]);
    float4 h0 = *(const float4*)(&h_s[rl][k]);
    float4 h1 = *(const float4*)(&h_s[rl][k + 4]);
    air = dot8(*(const uint4*)(wir + k), u0, u1, air);
    aiz = dot8(*(const uint4*)(wiz + k), u0, u1, aiz);
    ain = dot8(*(const uint4*)(win + k), u0, u1, ain);
    ahr = dot8(*(const uint4*)(whr + k), h0, h1, ahr);
    ahz = dot8(*(const uint4*)(whz + k), h0, h1, ahz);
    ahn = dot8(*(const uint4*)(whn + k), h0, h1, ahn);
  }
  float gr = air + bf1(bih[j])       + ahr + bf1(bhh[j]);
  float gz = aiz + bf1(bih[256 + j]) + ahz + bf1(bhh[256 + j]);
  float r = 1.f / (1.f + __expf(-gr));
  float z = 1.f / (1.f + __expf(-gz));
  float nn = tanhf(ain + bf1(bih[512 + j]) + r * (ahn + bf1(bhh[512 + j])));
  float h = h_s[rl][j];
  mid[row * 256 + j] = (1.f - z) * nn + z * h;
}

// ---------- K4b: LN + MLP + residual; non-last iters fuse next iter's k2
// (LN(res; gs,bs) -> qh) + next iter's denom/numer zeroing ----------
__global__ __launch_bounds__(256) void k4b_mlp(
    const float* __restrict__ mid, const u16* __restrict__ cw,
    float* __restrict__ slots, void* __restrict__ out_base,
    const int* __restrict__ flag, int lastIter,
    _Float16* __restrict__ qh, float* __restrict__ denom, float* __restrict__ numer,
    int zeroNumer)
{
  int f32m = *flag;
  const u16* gm = cw + CW_GM;
  const u16* bm = cw + CW_BM;
  const u16* w1 = cw + CW_W1;
  const u16* b1 = cw + CW_B1;
  const u16* w2 = cw + CW_W2;
  const u16* b2 = cw + CW_B2;
  int row = blockIdx.x, tid = threadIdx.x;
  int wv = tid >> 6, lane = tid & 63;
  float x = mid[row * 256 + tid];
  float s = x, s2 = x * x;
  #pragma unroll
  for (int m = 1; m < 64; m <<= 1){ s += __shfl_xor(s, m); s2 += __shfl_xor(s2, m); }
  __shared__ float red[8];
  if (lane == 0){ red[wv] = s; red[4 + wv] = s2; }
  __syncthreads();
  float tot  = red[0] + red[1] + red[2] + red[3];
  float tot2 = red[4] + red[5] + red[6] + red[7];
  float mu = tot * (1.f/256.f);
  float rstd = rsqrtf(tot2 * (1.f/256.f) - mu * mu + 1e-5f);
  __shared__ float ls[256];
  __shared__ float h1[512];
  ls[tid] = (x - mu) * rstd * bf1(gm[tid]) + bf1(bm[tid]);
  __syncthreads();
  const u16* w1a = w1 + tid * 256;
  const u16* w1b = w1 + (tid + 256) * 256;
  float a0 = 0.f, a1 = 0.f;
  for (int k = 0; k < 256; k += 8){
    float4 l0 = *(const float4*)(ls + k);
    float4 l1 = *(const float4*)(ls + k + 4);
    a0 = dot8(*(const uint4*)(w1a + k), l0, l1, a0);
    a1 = dot8(*(const uint4*)(w1b + k), l0, l1, a1);
  }
  h1[tid]       = fmaxf(a0 + bf1(b1[tid]), 0.f);
  h1[tid + 256] = fmaxf(a1 + bf1(b1[tid + 256]), 0.f);
  __syncthreads();
  const u16* w2r = w2 + tid * 512;
  float a = 0.f;
  for (int k = 0; k < 512; k += 8){
    float4 l0 = *(const float4*)(h1 + k);
    float4 l1 = *(const float4*)(h1 + k + 4);
    a = dot8(*(const uint4*)(w2r + k), l0, l1, a);
  }
  float res = x + a + bf1(b2[tid]);
  slots[row * 256 + tid] = res;
  if (lastIter){
    int idx = row * 256 + tid;
    if (f32m) ((float*)out_base)[idx] = res;
    else      ((u16*)out_base)[idx]   = f2bf(res);
  } else {
    // ---- fused next-iter k2: LN(res; gs,bs) -> qh = (Wq · sln) * scale ----
    // plus next iter's zeroing (k4a of this iter already consumed denom/numer)
    if (zeroNumer) numer[row * 256 + tid] = 0.f;   // 512*256 = 131072 exactly
    if (row < 16) denom[row * 256 + tid] = 0.f;    // 4096
    float s3 = res, s4 = res * res;
    #pragma unroll
    for (int m = 1; m < 64; m <<= 1){ s3 += __shfl_xor(s3, m); s4 += __shfl_xor(s4, m); }
    __syncthreads();                               // h1/ls reads done; reuse red
    if (lane == 0){ red[wv] = s3; red[4 + wv] = s4; }
    __syncthreads();
    float t1 = red[0] + red[1] + red[2] + red[3];
    float t2 = red[4] + red[5] + red[6] + red[7];
    float mu2 = t1 * (1.f/256.f);
    float rs2 = rsqrtf(t2 * (1.f/256.f) - mu2 * mu2 + 1e-5f);
    ls[tid] = (res - mu2) * rs2 * bf1(cw[CW_GS + tid]) + bf1(cw[CW_BS + tid]);
    __syncthreads();
    const u16* wr = cw + CW_WQ + tid * 256;
    float aq = 0.f;
    for (int k = 0; k < 256; k += 8){
      uint4 wu = *(const uint4*)(wr + k);
      float4 l0 = *(const float4*)(ls + k);
      float4 l1 = *(const float4*)(ls + k + 4);
      aq = dot8(wu, l0, l1, aq);
    }
    qh[row * 256 + tid] = (_Float16)(aq * 0.17677669529663687f);
  }
}

// ---------- launch ----------
extern "C" void kernel_launch(void* const* d_in, const int* in_sizes, int n_in,
                              void* d_out, int out_size, void* d_ws, size_t ws_size,
                              hipStream_t stream)
{
  char* ws = (char*)d_ws;
  int*  flagp    = (int*)ws;                        // [0,256)
  u16*  cw       = (u16*)(ws + 256);                // 1719808 -> 1720064
  _Float16* qh   = (_Float16*)(ws + 1720064);       //  262144 -> 1982208
  _Float16* wkvh = (_Float16*)(ws + 1982208);       //  262144 -> 2244352
  float* slots   = (float*)(ws + 2244352);          //  524288 -> 2768640
  float* mid     = (float*)(ws + 2768640);          //  524288 -> 3292928
  float* numer   = (float*)(ws + 3292928);          //  524288 -> 3817216
  float* denom   = (float*)(ws + 3817216);          //   16384 -> 3833600
  _Float16* kh   = (_Float16*)(ws + 3833600);       // 67108864 -> 70942464
  _Float16* vT   = (_Float16*)(ws + 70942464);      // 67108864 -> 138051328
  // aliases (dead before the iteration loop):
  float2* stats  = (float2*)(ws + 2768640);         // 1 MB over mid+numer
  float*  beta   = (float*)(ws + 3817216);          // 2 KB in denom region

  CanonArgs ca;
  ca.p[0]  = d_in[0];   ca.p[1]  = d_in[2];   ca.p[2]  = d_in[3];
  ca.p[3]  = d_in[4];   ca.p[4]  = d_in[5];   ca.p[5]  = d_in[6];
  ca.p[6]  = d_in[7];   ca.p[7]  = d_in[8];   ca.p[8]  = d_in[9];
  ca.p[9]  = d_in[10];  ca.p[10] = d_in[11];  ca.p[11] = d_in[12];
  ca.p[12] = d_in[13];  ca.p[13] = d_in[14];  ca.p[14] = d_in[15];
  ca.p[15] = d_in[16];  ca.p[16] = d_in[17];  ca.p[17] = d_in[18];

  k_flag<<<1, 256, 0, stream>>>((const u16*)d_in[1], flagp);
  k_canon<<<(CW_TOTAL + 255) / 256, 256, 0, stream>>>(ca, flagp, cw);
  k_init<<<1024, 256, 0, stream>>>(cw, slots, wkvh);
  k_beta<<<2, 256, 0, stream>>>(cw, beta);
  k0_stats<<<8192, 256, 0, stream>>>(d_in[1], flagp, stats);
  k1_gemm<<<1024, 512, 0, stream>>>(d_in[1], flagp, stats, beta, wkvh, kh, vT);
  // iter 0's qh + denom zeroing (k4b handles subsequent iters)
  k2_q<<<512, 256, 0, stream>>>(slots, cw, qh, denom);
  for (int it = 0; it < 3; it++){
    int last = (it == 2) ? 1 : 0;
    k3_attn<<<dim3(32, 16), 256, 0, stream>>>(kh, vT, qh, denom, numer, d_out, flagp, last);
    if (!last) k_reduce<<<512, 256, 0, stream>>>(d_out, flagp, numer);
    k4a_gru<<<dim3(8, 64), 256, 0, stream>>>(slots, numer, denom, cw, mid);
    k4b_mlp<<<512, 256, 0, stream>>>(mid, cw, slots, d_out, flagp, last,
                                     qh, denom, numer, (it == 1) ? 1 : 0);
  }
}